// Round 3
// baseline (226.166 us; speedup 1.0000x reference)
//
#include <hip/hip_runtime.h>

typedef unsigned int u32;
typedef unsigned long long u64;

#define N_PTS 480000
#define PPB   120000      // points per batch (B=4)
#define NKEY  131072      // 4 * 32^3 compact key space
#define NBLK_A 256
#define NBLK_B 512
#define NT64   7500       // N_PTS / 64
#define SLOPE 0.01f

// ---------------- kernel A: keys, per-voxel counts, x-moment partials ----------------
__global__ __launch_bounds__(256) void kA(const float* __restrict__ pc,
                                          const int* __restrict__ pidx,
                                          u32* __restrict__ keys,
                                          u32* __restrict__ cnt,
                                          float* __restrict__ pA) {
    int t = threadIdx.x;
    float a[14];
#pragma unroll
    for (int j = 0; j < 14; ++j) a[j] = 0.f;

    for (int n = blockIdx.x * 256 + t; n < N_PTS; n += gridDim.x * 256) {
        float4 x = ((const float4*)pc)[n];
        a[0] += x.x; a[1] += x.y; a[2] += x.z; a[3] += x.w;
        a[4] += x.x * x.x; a[5] += x.x * x.y; a[6]  += x.x * x.z; a[7]  += x.x * x.w;
        a[8] += x.y * x.y; a[9] += x.y * x.z; a[10] += x.y * x.w;
        a[11] += x.z * x.z; a[12] += x.z * x.w; a[13] += x.w * x.w;

        int i0 = pidx[3 * n], i1 = pidx[3 * n + 1], i2 = pidx[3 * n + 2];
        int bid = n / PPB;
        u32 key = (u32)(bid * 32768 + i0 * 1024 + i1 * 32 + i2);
        keys[n] = key;
        atomicAdd(&cnt[key], 1u);
    }

    __shared__ float red[256];
    for (int j = 0; j < 14; ++j) {
        red[t] = a[j];
        __syncthreads();
        for (int s = 128; s > 0; s >>= 1) {
            if (t < s) red[t] += red[t + s];
            __syncthreads();
        }
        if (t == 0) pA[blockIdx.x * 14 + j] = red[0];
        __syncthreads();
    }
}

// ---------------- kernel R1: reduce x-moments -> layer-1 BN scale/shift ----------------
__global__ __launch_bounds__(64) void kR1(const float* __restrict__ pA,
                                          const float* __restrict__ W1,
                                          const float* __restrict__ b1,
                                          const float* __restrict__ g1,
                                          const float* __restrict__ be1,
                                          float* __restrict__ stats1) {
    __shared__ double S[14];
    int t = threadIdx.x;
    if (t < 14) {
        double s = 0.0;
        for (int b = 0; b < NBLK_A; ++b) s += pA[b * 14 + t];
        S[t] = s;
    }
    __syncthreads();
    if (t < 16) {
        int c = t;
        double w[4];
#pragma unroll
        for (int i = 0; i < 4; ++i) w[i] = W1[i * 16 + c];
        double sx[4] = { S[0], S[1], S[2], S[3] };
        auto sxx = [&](int i, int j) -> double {
            if (i > j) { int k = i; i = j; j = k; }
            int base = (i == 0) ? 4 : (i == 1) ? 8 : (i == 2) ? 11 : 13;
            return S[base + (j - i)];
        };
        double su = 0.0;
        for (int i = 0; i < 4; ++i) su += sx[i] * w[i];
        double q = 0.0;
        for (int i = 0; i < 4; ++i)
            for (int j = 0; j < 4; ++j) q += w[i] * w[j] * sxx(i, j);
        double b = (double)b1[c];
        double sum   = su + b * (double)N_PTS;
        double sumsq = q + 2.0 * b * su + (double)N_PTS * b * b;
        double mean = sum / (double)N_PTS;
        double var  = sumsq / (double)N_PTS - mean * mean;
        float inv = rsqrtf((float)(var + 1e-5));
        float sc = g1[c] * inv;
        stats1[c]      = sc;
        stats1[16 + c] = be1[c] - (float)mean * sc;
    }
}

// ---------------- kernel B: h-moments (Sum h [16], Sum h h^T upper [136]) partials ----------------
__global__ __launch_bounds__(256) void kB(const float* __restrict__ pc,
                                          const float* __restrict__ W1,
                                          const float* __restrict__ b1,
                                          const float* __restrict__ stats1,
                                          float* __restrict__ pB) {
    int t = threadIdx.x;
    __shared__ float shx[256];
    __shared__ float shh[64][16];

    int c1 = t & 15;
    float w1c[4];
#pragma unroll
    for (int i = 0; i < 4; ++i) w1c[i] = W1[i * 16 + c1];
    float b1c = b1[c1], sc1 = stats1[c1], sf1 = stats1[16 + c1];

    // triangle pair mapping for q = t-16 in [0,136)
    int pi = 0, pj = 0;
    if (t >= 16 && t < 152) {
        int rem = t - 16, i = 0;
        while (rem >= 16 - i) { rem -= 16 - i; ++i; }
        pi = i; pj = i + rem;
    }

    float acc = 0.f;
    for (int tile = blockIdx.x; tile < NT64; tile += gridDim.x) {
        int base = tile * 64;
        shx[t] = pc[base * 4 + t];
        __syncthreads();
#pragma unroll
        for (int i = 0; i < 4; ++i) {
            int p = (t >> 4) + 16 * i;
            float hp = b1c + shx[p * 4 + 0] * w1c[0] + shx[p * 4 + 1] * w1c[1]
                           + shx[p * 4 + 2] * w1c[2] + shx[p * 4 + 3] * w1c[3];
            float z = hp * sc1 + sf1;
            shh[p][c1] = (z >= 0.f) ? z : SLOPE * z;
        }
        __syncthreads();
        if (t < 16) {
#pragma unroll 4
            for (int p = 0; p < 64; ++p) acc += shh[p][t];
        } else if (t < 152) {
#pragma unroll 4
            for (int p = 0; p < 64; ++p) acc += shh[p][pi] * shh[p][pj];
        }
        __syncthreads();
    }
    if (t < 152) pB[blockIdx.x * 152 + t] = acc;
}

// ---------------- kernel R2: h-moments + W2 -> layer-2 BN scale/shift ----------------
__global__ __launch_bounds__(256) void kR2(const float* __restrict__ pB,
                                           const float* __restrict__ W2,
                                           const float* __restrict__ b2,
                                           const float* __restrict__ g2,
                                           const float* __restrict__ be2,
                                           float* __restrict__ stats2) {
    __shared__ double S[152];
    int t = threadIdx.x;
    if (t < 152) {
        double s = 0.0;
        for (int b = 0; b < NBLK_B; ++b) s += pB[b * 152 + t];
        S[t] = s;
    }
    __syncthreads();
    if (t < 64) {
        double w[16];
#pragma unroll
        for (int k = 0; k < 16; ++k) w[k] = W2[k * 64 + t];
        double sh = 0.0;
        for (int k = 0; k < 16; ++k) sh += w[k] * S[k];
        auto qidx = [&](int i, int j) { return 16 + i * 16 - (i * (i - 1)) / 2 + (j - i); };
        double q = 0.0;
        for (int i = 0; i < 16; ++i) {
            q += w[i] * w[i] * S[qidx(i, i)];
            double t2 = 0.0;
            for (int j = i + 1; j < 16; ++j) t2 += w[j] * S[qidx(i, j)];
            q += 2.0 * w[i] * t2;
        }
        double b = (double)b2[t];
        double sum   = sh + b * (double)N_PTS;
        double sumsq = q + 2.0 * b * sh + (double)N_PTS * b * b;
        double mean = sum / (double)N_PTS;
        double var  = sumsq / (double)N_PTS - mean * mean;
        float inv = rsqrtf((float)(var + 1e-5));
        float sc = g2[t] * inv;
        stats2[t]      = sc;
        stats2[64 + t] = be2[t] - (float)mean * sc;
    }
}

// ---------------- scan pass 1: per-block sums of counts and occupancy ----------------
__global__ __launch_bounds__(256) void kS1(const u32* __restrict__ cnt,
                                           u32* __restrict__ bsum) {
    int t = threadIdx.x, b = blockIdx.x;
    uint4 c4 = ((const uint4*)cnt)[b * 256 + t];
    u32 cs = c4.x + c4.y + c4.z + c4.w;
    u32 os = (c4.x > 0) + (c4.y > 0) + (c4.z > 0) + (c4.w > 0);
    __shared__ u32 rc[256], ro[256];
    rc[t] = cs; ro[t] = os;
    __syncthreads();
    for (int s = 128; s > 0; s >>= 1) {
        if (t < s) { rc[t] += rc[t + s]; ro[t] += ro[t + s]; }
        __syncthreads();
    }
    if (t == 0) { bsum[2 * b] = rc[0]; bsum[2 * b + 1] = ro[0]; }
}

// ---------------- scan pass 2: cursors (in-place over cnt), startc, vi rows, n_uni ----------------
__global__ __launch_bounds__(256) void kS2(u32* __restrict__ cnt,        // becomes cursor
                                           const u32* __restrict__ bsum,
                                           u32* __restrict__ startc,
                                           float* __restrict__ vi,
                                           u32* __restrict__ nuni) {
    int t = threadIdx.x, b = blockIdx.x;
    __shared__ u32 sbc[128], sbo[128];
    __shared__ u32 cOff, oOff;
    __shared__ u64 scan[256];
    if (t < 128) { sbc[t] = bsum[2 * t]; sbo[t] = bsum[2 * t + 1]; }

    uint4 c4 = ((const uint4*)cnt)[b * 256 + t];
    u32 cv[4] = { c4.x, c4.y, c4.z, c4.w };
    u32 cs = cv[0] + cv[1] + cv[2] + cv[3];
    u32 os = (cv[0] > 0) + (cv[1] > 0) + (cv[2] > 0) + (cv[3] > 0);
    scan[t] = ((u64)cs << 32) | (u64)os;
    __syncthreads();
    if (t == 0) {
        u32 a = 0, o = 0;
        for (int i = 0; i < b; ++i) { a += sbc[i]; o += sbo[i]; }
        cOff = a; oOff = o;
    }
    for (int d = 1; d < 256; d <<= 1) {
        u64 v = (t >= d) ? scan[t - d] : 0ull;
        __syncthreads();
        scan[t] += v;
        __syncthreads();
    }
    u64 ex = scan[t] - (((u64)cs << 32) | (u64)os);
    u32 start = cOff + (u32)(ex >> 32);
    u32 rank  = oOff + (u32)(ex & 0xffffffffull);

    int kbase = b * 1024 + t * 4;
#pragma unroll
    for (int j = 0; j < 4; ++j) {
        u32 k = (u32)(kbase + j);
        cnt[k] = start;                     // cursor = exclusive start
        if (cv[j] > 0) {
            startc[rank] = start;
            float4 o;
            o.x = (float)(k >> 15);
            o.y = (float)((k >> 10) & 31);
            o.z = (float)((k >> 5) & 31);
            o.w = (float)(k & 31);
            ((float4*)vi)[rank] = o;
            rank++;
        }
        start += cv[j];
    }
    if (b == 127 && t == 255) {
        nuni[0] = rank;
        startc[rank] = N_PTS;               // sentinel
    }
}

// ---------------- kernel P: scatter point ids into voxel-sorted order ----------------
__global__ __launch_bounds__(256) void kP(const u32* __restrict__ keys,
                                          u32* __restrict__ cursor,
                                          u32* __restrict__ pid) {
    int n = blockIdx.x * 256 + threadIdx.x;
    if (n < N_PTS) {
        u32 k = keys[n];
        u32 pos = atomicAdd(&cursor[k], 1u);
        pid[pos] = (u32)n;
    }
}

// ---------------- kernel C: final MLP, write feat (no atomics) ----------------
__global__ __launch_bounds__(256) void kC(const float* __restrict__ pc,
                                          const float* __restrict__ W1,
                                          const float* __restrict__ b1,
                                          const float* __restrict__ stats1,
                                          const float* __restrict__ W2,
                                          const float* __restrict__ b2,
                                          const float* __restrict__ stats2,
                                          float* __restrict__ feat_out) {
    int t = threadIdx.x;
    __shared__ float shx[256];
    __shared__ float shh[64][16];

    int c1 = t & 15;
    float w1c[4];
#pragma unroll
    for (int i = 0; i < 4; ++i) w1c[i] = W1[i * 16 + c1];
    float b1c = b1[c1], sc1 = stats1[c1], sf1 = stats1[16 + c1];

    int c2 = t & 63;
    float w2c[16];
#pragma unroll
    for (int k = 0; k < 16; ++k) w2c[k] = W2[k * 64 + c2];
    float b2c = b2[c2], sc2 = stats2[c2], sf2 = stats2[64 + c2];
    int pg = t >> 6;

    for (int tile = blockIdx.x; tile < NT64; tile += gridDim.x) {
        int base = tile * 64;
        shx[t] = pc[base * 4 + t];
        __syncthreads();
#pragma unroll
        for (int i = 0; i < 4; ++i) {
            int p = (t >> 4) + 16 * i;
            float hp = b1c + shx[p * 4 + 0] * w1c[0] + shx[p * 4 + 1] * w1c[1]
                           + shx[p * 4 + 2] * w1c[2] + shx[p * 4 + 3] * w1c[3];
            float z = hp * sc1 + sf1;
            shh[p][c1] = (z >= 0.f) ? z : SLOPE * z;
        }
        __syncthreads();
#pragma unroll
        for (int j = 0; j < 16; ++j) {
            int p = pg + 4 * j;
            float f = b2c;
#pragma unroll
            for (int k = 0; k < 16; ++k) f += shh[p][k] * w2c[k];
            float z = f * sc2 + sf2;
            float ff = (z >= 0.f) ? z : SLOPE * z;
            feat_out[(size_t)(base + p) * 64 + c2] = ff;
        }
        __syncthreads();
    }
}

// ---------------- kernel V: gather-max per voxel rank; zero tails ----------------
__global__ __launch_bounds__(256) void kV(const float* __restrict__ feat,
                                          const u32* __restrict__ pid,
                                          const u32* __restrict__ startc,
                                          const u32* __restrict__ nuni,
                                          float* __restrict__ vf,
                                          float* __restrict__ vi) {
    u32 nu = *nuni;
    u32 r0 = blockIdx.x * 4;
    int w = threadIdx.x >> 6, lane = threadIdx.x & 63;

    // zero vi tail rows for this block's 4 ranks (coalesced 64B)
    if (threadIdx.x < 16) {
        u32 row = r0 + (threadIdx.x >> 2);
        if (row >= nu) vi[(size_t)row * 4 + (threadIdx.x & 3)] = 0.f;
    }

    u32 r = r0 + (u32)w;
    if (r < nu) {
        u32 s = startc[r], e = startc[r + 1];
        float m = -3.4e38f;
        for (u32 i = s; i < e; ++i) {
            u32 p = pid[i];
            m = fmaxf(m, feat[(size_t)p * 64 + lane]);
        }
        vf[(size_t)r * 64 + lane] = m;
    } else {
        vf[(size_t)r * 64 + lane] = 0.f;
    }
}

extern "C" void kernel_launch(void* const* d_in, const int* in_sizes, int n_in,
                              void* d_out, int out_size, void* d_ws, size_t ws_size,
                              hipStream_t stream) {
    const float* pc   = (const float*)d_in[0];
    const int*   pidx = (const int*)d_in[1];
    const float* W1   = (const float*)d_in[2];
    const float* b1   = (const float*)d_in[3];
    const float* g1   = (const float*)d_in[4];
    const float* be1  = (const float*)d_in[5];
    const float* W2   = (const float*)d_in[6];
    const float* b2   = (const float*)d_in[7];
    const float* g2   = (const float*)d_in[8];
    const float* be2  = (const float*)d_in[9];

    float* vf   = (float*)d_out;                    // [N,64]
    float* vi   = vf + (size_t)N_PTS * 64;          // [N,4]
    float* feat = vi + (size_t)N_PTS * 4;           // [N,64]

    u32* ws     = (u32*)d_ws;
    u32* keys   = ws;                        // 480000
    u32* cnt    = ws + 480000;               // 131072 (becomes cursor in kS2)
    u32* startc = ws + 611072;               // 131073 (+pad to 131076)
    u32* bsum   = ws + 742148;               // 256
    u32* nuni   = ws + 742404;               // 1 (+pad)
    u32* pid    = ws + 742420;               // 480000
    float* pA     = (float*)(ws + 1222420);  // 256*14 = 3584
    float* stats1 = (float*)(ws + 1226004);  // 32
    float* pB     = (float*)(ws + 1226036);  // 512*152 = 77824
    float* stats2 = (float*)(ws + 1303860);  // 128

    hipMemsetAsync(cnt, 0, (size_t)NKEY * 4, stream);

    kA<<<NBLK_A, 256, 0, stream>>>(pc, pidx, keys, cnt, pA);
    kR1<<<1, 64, 0, stream>>>(pA, W1, b1, g1, be1, stats1);
    kB<<<NBLK_B, 256, 0, stream>>>(pc, W1, b1, stats1, pB);
    kR2<<<1, 256, 0, stream>>>(pB, W2, b2, g2, be2, stats2);
    kS1<<<128, 256, 0, stream>>>(cnt, bsum);
    kS2<<<128, 256, 0, stream>>>(cnt, bsum, startc, vi, nuni);
    kP<<<1875, 256, 0, stream>>>(keys, cnt, pid);
    kC<<<2048, 256, 0, stream>>>(pc, W1, b1, stats1, W2, b2, stats2, feat);
    kV<<<120000, 256, 0, stream>>>(feat, pid, startc, nuni, vf, vi);
}

// Round 4
// 215.853 us; speedup vs baseline: 1.0478x; 1.0478x over previous
//
#include <hip/hip_runtime.h>

typedef unsigned int u32;
typedef unsigned long long u64;

#define N_PTS 480000
#define PPB   120000      // points per batch (B=4)
#define NKEY  131072      // 4 * 32^3 compact key space
#define NBLK_A 256
#define NBLK_B 512
#define NT64   7500       // N_PTS / 64
#define SLOPE 0.01f

// ---------------- kernel Z: zero the count table (replaces memset node) ----------------
__global__ __launch_bounds__(256) void kZ(u32* __restrict__ cnt) {
    uint4 z; z.x = 0u; z.y = 0u; z.z = 0u; z.w = 0u;
    ((uint4*)cnt)[blockIdx.x * 256 + threadIdx.x] = z;   // 128 blocks * 256 * 16B = 512KB
}

// ---------------- kernel A: keys, per-voxel counts, x-moment partials (moment-major) ----------------
__global__ __launch_bounds__(256) void kA(const float* __restrict__ pc,
                                          const int* __restrict__ pidx,
                                          u32* __restrict__ keys,
                                          u32* __restrict__ cnt,
                                          float* __restrict__ pA) {
    int t = threadIdx.x;
    float a[14];
#pragma unroll
    for (int j = 0; j < 14; ++j) a[j] = 0.f;

    for (int n = blockIdx.x * 256 + t; n < N_PTS; n += gridDim.x * 256) {
        float4 x = ((const float4*)pc)[n];
        a[0] += x.x; a[1] += x.y; a[2] += x.z; a[3] += x.w;
        a[4] += x.x * x.x; a[5] += x.x * x.y; a[6]  += x.x * x.z; a[7]  += x.x * x.w;
        a[8] += x.y * x.y; a[9] += x.y * x.z; a[10] += x.y * x.w;
        a[11] += x.z * x.z; a[12] += x.z * x.w; a[13] += x.w * x.w;

        int i0 = pidx[3 * n], i1 = pidx[3 * n + 1], i2 = pidx[3 * n + 2];
        int bid = n / PPB;
        u32 key = (u32)(bid * 32768 + i0 * 1024 + i1 * 32 + i2);
        keys[n] = key;
        atomicAdd(&cnt[key], 1u);
    }

    __shared__ float red[256];
    for (int j = 0; j < 14; ++j) {
        red[t] = a[j];
        __syncthreads();
        for (int s = 128; s > 0; s >>= 1) {
            if (t < s) red[t] += red[t + s];
            __syncthreads();
        }
        if (t == 0) pA[j * NBLK_A + blockIdx.x] = red[0];   // moment-major
        __syncthreads();
    }
}

// ---------------- kernel R1: wave-parallel reduce of x-moments -> layer-1 BN scale/shift ----------------
__global__ __launch_bounds__(1024) void kR1(const float* __restrict__ pA,
                                            const float* __restrict__ W1,
                                            const float* __restrict__ b1,
                                            const float* __restrict__ g1,
                                            const float* __restrict__ be1,
                                            float* __restrict__ stats1) {
    int t = threadIdx.x, w = t >> 6, lane = t & 63;
    __shared__ float S[14];
    if (w < 14) {
        const float* p = pA + w * NBLK_A;
        float s = p[lane] + p[lane + 64] + p[lane + 128] + p[lane + 192];
        for (int d = 32; d > 0; d >>= 1) s += __shfl_xor(s, d);
        if (lane == 0) S[w] = s;
    }
    __syncthreads();
    if (t < 16) {
        int c = t;
        double w4[4];
#pragma unroll
        for (int i = 0; i < 4; ++i) w4[i] = W1[i * 16 + c];
        double sx[4] = { S[0], S[1], S[2], S[3] };
        auto sxx = [&](int i, int j) -> double {
            if (i > j) { int k = i; i = j; j = k; }
            int base = (i == 0) ? 4 : (i == 1) ? 8 : (i == 2) ? 11 : 13;
            return (double)S[base + (j - i)];
        };
        double su = 0.0;
        for (int i = 0; i < 4; ++i) su += sx[i] * w4[i];
        double q = 0.0;
        for (int i = 0; i < 4; ++i)
            for (int j = 0; j < 4; ++j) q += w4[i] * w4[j] * sxx(i, j);
        double b = (double)b1[c];
        double sum   = su + b * (double)N_PTS;
        double sumsq = q + 2.0 * b * su + (double)N_PTS * b * b;
        double mean = sum / (double)N_PTS;
        double var  = sumsq / (double)N_PTS - mean * mean;
        float inv = rsqrtf((float)(var + 1e-5));
        float sc = g1[c] * inv;
        stats1[c]      = sc;
        stats1[16 + c] = be1[c] - (float)mean * sc;
    }
}

// ---------------- kernel B: h-moment partials (moment-major pB[152][512]) ----------------
__global__ __launch_bounds__(256) void kB(const float* __restrict__ pc,
                                          const float* __restrict__ W1,
                                          const float* __restrict__ b1,
                                          const float* __restrict__ stats1,
                                          float* __restrict__ pB) {
    int t = threadIdx.x;
    __shared__ float shx[256];
    __shared__ float shh[64][16];

    int c1 = t & 15;
    float w1c[4];
#pragma unroll
    for (int i = 0; i < 4; ++i) w1c[i] = W1[i * 16 + c1];
    float b1c = b1[c1], sc1 = stats1[c1], sf1 = stats1[16 + c1];

    // triangle pair mapping for q = t-16 in [0,136)
    int pi = 0, pj = 0;
    if (t >= 16 && t < 152) {
        int rem = t - 16, i = 0;
        while (rem >= 16 - i) { rem -= 16 - i; ++i; }
        pi = i; pj = i + rem;
    }

    float acc = 0.f;
    for (int tile = blockIdx.x; tile < NT64; tile += gridDim.x) {
        int base = tile * 64;
        shx[t] = pc[base * 4 + t];
        __syncthreads();
#pragma unroll
        for (int i = 0; i < 4; ++i) {
            int p = (t >> 4) + 16 * i;
            float hp = b1c + shx[p * 4 + 0] * w1c[0] + shx[p * 4 + 1] * w1c[1]
                           + shx[p * 4 + 2] * w1c[2] + shx[p * 4 + 3] * w1c[3];
            float z = hp * sc1 + sf1;
            shh[p][c1] = (z >= 0.f) ? z : SLOPE * z;
        }
        __syncthreads();
        if (t < 16) {
#pragma unroll 4
            for (int p = 0; p < 64; ++p) acc += shh[p][t];
        } else if (t < 152) {
#pragma unroll 4
            for (int p = 0; p < 64; ++p) acc += shh[p][pi] * shh[p][pj];
        }
        __syncthreads();
    }
    if (t < 152) pB[t * NBLK_B + blockIdx.x] = acc;   // moment-major
}

// ---------------- kernel R2: wave-parallel reduce h-moments -> layer-2 BN scale/shift ----------------
__global__ __launch_bounds__(1024) void kR2(const float* __restrict__ pB,
                                            const float* __restrict__ W2,
                                            const float* __restrict__ b2,
                                            const float* __restrict__ g2,
                                            const float* __restrict__ be2,
                                            float* __restrict__ stats2) {
    int t = threadIdx.x, w = t >> 6, lane = t & 63;
    __shared__ float S[152];
    for (int q = w; q < 152; q += 16) {
        const float* p = pB + q * NBLK_B;
        float s = 0.f;
#pragma unroll
        for (int b = 0; b < 8; ++b) s += p[b * 64 + lane];
        for (int d = 32; d > 0; d >>= 1) s += __shfl_xor(s, d);
        if (lane == 0) S[q] = s;
    }
    __syncthreads();
    if (t < 64) {
        double wv[16];
#pragma unroll
        for (int k = 0; k < 16; ++k) wv[k] = W2[k * 64 + t];
        double sh = 0.0;
        for (int k = 0; k < 16; ++k) sh += wv[k] * (double)S[k];
        auto qidx = [&](int i, int j) { return 16 + i * 16 - (i * (i - 1)) / 2 + (j - i); };
        double q = 0.0;
        for (int i = 0; i < 16; ++i) {
            q += wv[i] * wv[i] * (double)S[qidx(i, i)];
            double t2 = 0.0;
            for (int j = i + 1; j < 16; ++j) t2 += wv[j] * (double)S[qidx(i, j)];
            q += 2.0 * wv[i] * t2;
        }
        double b = (double)b2[t];
        double sum   = sh + b * (double)N_PTS;
        double sumsq = q + 2.0 * b * sh + (double)N_PTS * b * b;
        double mean = sum / (double)N_PTS;
        double var  = sumsq / (double)N_PTS - mean * mean;
        float inv = rsqrtf((float)(var + 1e-5));
        float sc = g2[t] * inv;
        stats2[t]      = sc;
        stats2[64 + t] = be2[t] - (float)mean * sc;
    }
}

// ---------------- scan pass 1: per-block sums of counts and occupancy ----------------
__global__ __launch_bounds__(256) void kS1(const u32* __restrict__ cnt,
                                           u32* __restrict__ bsum) {
    int t = threadIdx.x, b = blockIdx.x;
    uint4 c4 = ((const uint4*)cnt)[b * 256 + t];
    u32 cs = c4.x + c4.y + c4.z + c4.w;
    u32 os = (c4.x > 0) + (c4.y > 0) + (c4.z > 0) + (c4.w > 0);
    __shared__ u32 rc[256], ro[256];
    rc[t] = cs; ro[t] = os;
    __syncthreads();
    for (int s = 128; s > 0; s >>= 1) {
        if (t < s) { rc[t] += rc[t + s]; ro[t] += ro[t + s]; }
        __syncthreads();
    }
    if (t == 0) { bsum[2 * b] = rc[0]; bsum[2 * b + 1] = ro[0]; }
}

// ---------------- scan pass 2: cursors (in-place over cnt), startc, vi rows, n_uni ----------------
__global__ __launch_bounds__(256) void kS2(u32* __restrict__ cnt,        // becomes cursor
                                           const u32* __restrict__ bsum,
                                           u32* __restrict__ startc,
                                           float* __restrict__ vi,
                                           u32* __restrict__ nuni) {
    int t = threadIdx.x, b = blockIdx.x;
    __shared__ u32 sbc[128], sbo[128];
    __shared__ u32 cOff, oOff;
    __shared__ u64 scan[256];
    if (t < 128) { sbc[t] = bsum[2 * t]; sbo[t] = bsum[2 * t + 1]; }

    uint4 c4 = ((const uint4*)cnt)[b * 256 + t];
    u32 cv[4] = { c4.x, c4.y, c4.z, c4.w };
    u32 cs = cv[0] + cv[1] + cv[2] + cv[3];
    u32 os = (cv[0] > 0) + (cv[1] > 0) + (cv[2] > 0) + (cv[3] > 0);
    scan[t] = ((u64)cs << 32) | (u64)os;
    __syncthreads();
    if (t == 0) {
        u32 a = 0, o = 0;
        for (int i = 0; i < b; ++i) { a += sbc[i]; o += sbo[i]; }
        cOff = a; oOff = o;
    }
    for (int d = 1; d < 256; d <<= 1) {
        u64 v = (t >= d) ? scan[t - d] : 0ull;
        __syncthreads();
        scan[t] += v;
        __syncthreads();
    }
    u64 ex = scan[t] - (((u64)cs << 32) | (u64)os);
    u32 start = cOff + (u32)(ex >> 32);
    u32 rank  = oOff + (u32)(ex & 0xffffffffull);

    int kbase = b * 1024 + t * 4;
#pragma unroll
    for (int j = 0; j < 4; ++j) {
        u32 k = (u32)(kbase + j);
        cnt[k] = start;                     // cursor = exclusive start
        if (cv[j] > 0) {
            startc[rank] = start;
            float4 o;
            o.x = (float)(k >> 15);
            o.y = (float)((k >> 10) & 31);
            o.z = (float)((k >> 5) & 31);
            o.w = (float)(k & 31);
            ((float4*)vi)[rank] = o;
            rank++;
        }
        start += cv[j];
    }
    if (b == 127 && t == 255) {
        nuni[0] = rank;
        startc[rank] = N_PTS;               // sentinel
    }
}

// ---------------- kernel P: scatter point ids into voxel-sorted order ----------------
__global__ __launch_bounds__(256) void kP(const u32* __restrict__ keys,
                                          u32* __restrict__ cursor,
                                          u32* __restrict__ pid) {
    int n = blockIdx.x * 256 + threadIdx.x;
    if (n < N_PTS) {
        u32 k = keys[n];
        u32 pos = atomicAdd(&cursor[k], 1u);
        pid[pos] = (u32)n;
    }
}

// ---------------- kernel C: final MLP, write feat (no atomics) ----------------
__global__ __launch_bounds__(256) void kC(const float* __restrict__ pc,
                                          const float* __restrict__ W1,
                                          const float* __restrict__ b1,
                                          const float* __restrict__ stats1,
                                          const float* __restrict__ W2,
                                          const float* __restrict__ b2,
                                          const float* __restrict__ stats2,
                                          float* __restrict__ feat_out) {
    int t = threadIdx.x;
    __shared__ float shx[256];
    __shared__ float shh[64][16];

    int c1 = t & 15;
    float w1c[4];
#pragma unroll
    for (int i = 0; i < 4; ++i) w1c[i] = W1[i * 16 + c1];
    float b1c = b1[c1], sc1 = stats1[c1], sf1 = stats1[16 + c1];

    int c2 = t & 63;
    float w2c[16];
#pragma unroll
    for (int k = 0; k < 16; ++k) w2c[k] = W2[k * 64 + c2];
    float b2c = b2[c2], sc2 = stats2[c2], sf2 = stats2[64 + c2];
    int pg = t >> 6;

    for (int tile = blockIdx.x; tile < NT64; tile += gridDim.x) {
        int base = tile * 64;
        shx[t] = pc[base * 4 + t];
        __syncthreads();
#pragma unroll
        for (int i = 0; i < 4; ++i) {
            int p = (t >> 4) + 16 * i;
            float hp = b1c + shx[p * 4 + 0] * w1c[0] + shx[p * 4 + 1] * w1c[1]
                           + shx[p * 4 + 2] * w1c[2] + shx[p * 4 + 3] * w1c[3];
            float z = hp * sc1 + sf1;
            shh[p][c1] = (z >= 0.f) ? z : SLOPE * z;
        }
        __syncthreads();
#pragma unroll
        for (int j = 0; j < 16; ++j) {
            int p = pg + 4 * j;
            float f = b2c;
#pragma unroll
            for (int k = 0; k < 16; ++k) f += shh[p][k] * w2c[k];
            float z = f * sc2 + sf2;
            float ff = (z >= 0.f) ? z : SLOPE * z;
            feat_out[(size_t)(base + p) * 64 + c2] = ff;
        }
        __syncthreads();
    }
}

// ---------------- kernel V: gather-max per voxel rank; zero tails ----------------
__global__ __launch_bounds__(256) void kV(const float* __restrict__ feat,
                                          const u32* __restrict__ pid,
                                          const u32* __restrict__ startc,
                                          const u32* __restrict__ nuni,
                                          float* __restrict__ vf,
                                          float* __restrict__ vi) {
    u32 nu = *nuni;
    u32 r0 = blockIdx.x * 4;
    int w = threadIdx.x >> 6, lane = threadIdx.x & 63;

    // zero vi tail rows for this block's 4 ranks (coalesced 64B)
    if (threadIdx.x < 16) {
        u32 row = r0 + (threadIdx.x >> 2);
        if (row >= nu) vi[(size_t)row * 4 + (threadIdx.x & 3)] = 0.f;
    }

    u32 r = r0 + (u32)w;
    if (r < nu) {
        u32 s = startc[r], e = startc[r + 1];
        float m = -3.4e38f;
        for (u32 i = s; i < e; ++i) {
            u32 p = pid[i];
            m = fmaxf(m, feat[(size_t)p * 64 + lane]);
        }
        vf[(size_t)r * 64 + lane] = m;
    } else {
        vf[(size_t)r * 64 + lane] = 0.f;
    }
}

extern "C" void kernel_launch(void* const* d_in, const int* in_sizes, int n_in,
                              void* d_out, int out_size, void* d_ws, size_t ws_size,
                              hipStream_t stream) {
    const float* pc   = (const float*)d_in[0];
    const int*   pidx = (const int*)d_in[1];
    const float* W1   = (const float*)d_in[2];
    const float* b1   = (const float*)d_in[3];
    const float* g1   = (const float*)d_in[4];
    const float* be1  = (const float*)d_in[5];
    const float* W2   = (const float*)d_in[6];
    const float* b2   = (const float*)d_in[7];
    const float* g2   = (const float*)d_in[8];
    const float* be2  = (const float*)d_in[9];

    float* vf   = (float*)d_out;                    // [N,64]
    float* vi   = vf + (size_t)N_PTS * 64;          // [N,4]
    float* feat = vi + (size_t)N_PTS * 4;           // [N,64]

    u32* ws     = (u32*)d_ws;
    u32* keys   = ws;                        // 480000
    u32* cnt    = ws + 480000;               // 131072 (becomes cursor in kS2)
    u32* startc = ws + 611072;               // 131073 (+pad to 131076)
    u32* bsum   = ws + 742148;               // 256
    u32* nuni   = ws + 742404;               // 1 (+pad)
    u32* pid    = ws + 742420;               // 480000
    float* pA     = (float*)(ws + 1222420);  // 14*256 = 3584
    float* stats1 = (float*)(ws + 1226004);  // 32
    float* pB     = (float*)(ws + 1226036);  // 152*512 = 77824
    float* stats2 = (float*)(ws + 1303860);  // 128

    kZ<<<128, 256, 0, stream>>>(cnt);
    kA<<<NBLK_A, 256, 0, stream>>>(pc, pidx, keys, cnt, pA);
    kR1<<<1, 1024, 0, stream>>>(pA, W1, b1, g1, be1, stats1);
    kB<<<NBLK_B, 256, 0, stream>>>(pc, W1, b1, stats1, pB);
    kR2<<<1, 1024, 0, stream>>>(pB, W2, b2, g2, be2, stats2);
    kS1<<<128, 256, 0, stream>>>(cnt, bsum);
    kS2<<<128, 256, 0, stream>>>(cnt, bsum, startc, vi, nuni);
    kP<<<1875, 256, 0, stream>>>(keys, cnt, pid);
    kC<<<2048, 256, 0, stream>>>(pc, W1, b1, stats1, W2, b2, stats2, feat);
    kV<<<120000, 256, 0, stream>>>(feat, pid, startc, nuni, vf, vi);
}

// Round 5
// 204.936 us; speedup vs baseline: 1.1036x; 1.0533x over previous
//
#include <hip/hip_runtime.h>

typedef unsigned int u32;
typedef unsigned long long u64;

#define N_PTS 480000
#define PPB   120000      // points per batch (B=4)
#define NKEY  131072      // 4 * 32^3 compact key space
#define NBLK_A 256
#define NBLK_B 256
#define NT64   7500       // N_PTS / 64
#define SLOPE 0.01f

__device__ __forceinline__ u32 bf16pack(float lo, float hi) {
    u32 a = __float_as_uint(lo), b = __float_as_uint(hi);
    a += 0x7fffu + ((a >> 16) & 1u);   // RNE
    b += 0x7fffu + ((b >> 16) & 1u);
    return (a >> 16) | (b & 0xffff0000u);
}
__device__ __forceinline__ float bf_lo(u32 v) { return __uint_as_float(v << 16); }
__device__ __forceinline__ float bf_hi(u32 v) { return __uint_as_float(v & 0xffff0000u); }

// ---------------- kernel Z: zero the count table ----------------
__global__ __launch_bounds__(256) void kZ(u32* __restrict__ cnt) {
    uint4 z; z.x = 0u; z.y = 0u; z.z = 0u; z.w = 0u;
    ((uint4*)cnt)[blockIdx.x * 256 + threadIdx.x] = z;   // 128*256*16B = 512KB
}

// ---------------- kernel A: keys, per-voxel counts, x-moment partials ----------------
__global__ __launch_bounds__(256) void kA(const float* __restrict__ pc,
                                          const int* __restrict__ pidx,
                                          u32* __restrict__ keys,
                                          u32* __restrict__ cnt,
                                          float* __restrict__ pA) {
    int t = threadIdx.x;
    float a[14];
#pragma unroll
    for (int j = 0; j < 14; ++j) a[j] = 0.f;

    for (int n = blockIdx.x * 256 + t; n < N_PTS; n += gridDim.x * 256) {
        float4 x = ((const float4*)pc)[n];
        a[0] += x.x; a[1] += x.y; a[2] += x.z; a[3] += x.w;
        a[4] += x.x * x.x; a[5] += x.x * x.y; a[6]  += x.x * x.z; a[7]  += x.x * x.w;
        a[8] += x.y * x.y; a[9] += x.y * x.z; a[10] += x.y * x.w;
        a[11] += x.z * x.z; a[12] += x.z * x.w; a[13] += x.w * x.w;

        int i0 = pidx[3 * n], i1 = pidx[3 * n + 1], i2 = pidx[3 * n + 2];
        int bid = n / PPB;
        u32 key = (u32)(bid * 32768 + i0 * 1024 + i1 * 32 + i2);
        keys[n] = key;
        atomicAdd(&cnt[key], 1u);
    }

    __shared__ float red[256];
    for (int j = 0; j < 14; ++j) {
        red[t] = a[j];
        __syncthreads();
        for (int s = 128; s > 0; s >>= 1) {
            if (t < s) red[t] += red[t + s];
            __syncthreads();
        }
        if (t == 0) pA[j * NBLK_A + blockIdx.x] = red[0];   // moment-major
        __syncthreads();
    }
}

// ---------------- kernel R1: reduce x-moments -> folded layer-1 weights ----------------
// stats1 layout: [c*4+i] = W1[i][c]*sc1[c]  (c-major, 64) ; [64+c] = b1[c]*sc1[c]+sf1[c]
__global__ __launch_bounds__(1024) void kR1(const float* __restrict__ pA,
                                            const float* __restrict__ W1,
                                            const float* __restrict__ b1,
                                            const float* __restrict__ g1,
                                            const float* __restrict__ be1,
                                            float* __restrict__ stats1) {
    int t = threadIdx.x, w = t >> 6, lane = t & 63;
    __shared__ float S[14];
    if (w < 14) {
        const float* p = pA + w * NBLK_A;
        float s = p[lane] + p[lane + 64] + p[lane + 128] + p[lane + 192];
        for (int d = 32; d > 0; d >>= 1) s += __shfl_xor(s, d);
        if (lane == 0) S[w] = s;
    }
    __syncthreads();
    if (t < 16) {
        int c = t;
        double w4[4];
#pragma unroll
        for (int i = 0; i < 4; ++i) w4[i] = W1[i * 16 + c];
        double sx[4] = { S[0], S[1], S[2], S[3] };
        auto sxx = [&](int i, int j) -> double {
            if (i > j) { int k = i; i = j; j = k; }
            int base = (i == 0) ? 4 : (i == 1) ? 8 : (i == 2) ? 11 : 13;
            return (double)S[base + (j - i)];
        };
        double su = 0.0;
        for (int i = 0; i < 4; ++i) su += sx[i] * w4[i];
        double q = 0.0;
        for (int i = 0; i < 4; ++i)
            for (int j = 0; j < 4; ++j) q += w4[i] * w4[j] * sxx(i, j);
        double b = (double)b1[c];
        double sum   = su + b * (double)N_PTS;
        double sumsq = q + 2.0 * b * su + (double)N_PTS * b * b;
        double mean = sum / (double)N_PTS;
        double var  = sumsq / (double)N_PTS - mean * mean;
        float inv = rsqrtf((float)(var + 1e-5));
        float sc = g1[c] * inv;
        float sf = be1[c] - (float)mean * sc;
#pragma unroll
        for (int i = 0; i < 4; ++i) stats1[c * 4 + i] = W1[i * 16 + c] * sc;
        stats1[64 + c] = b1[c] * sc + sf;
    }
}

// ---------------- kernel B: register h-moments (Sum h [16], Sum h h^T upper [136]) ----------------
__global__ __launch_bounds__(256, 1) void kB(const float* __restrict__ pc,
                                             const float* __restrict__ stats1,
                                             float* __restrict__ pB) {
    int t = threadIdx.x, w = t >> 6, lane = t & 63;
    __shared__ float sW[80];
    __shared__ float sred[4][152];
    if (t < 80) sW[t] = stats1[t];
    __syncthreads();

    float acc[152];
#pragma unroll
    for (int m = 0; m < 152; ++m) acc[m] = 0.f;

    const float4* sW4 = (const float4*)sW;
    for (int n = blockIdx.x * 256 + t; n < N_PTS; n += NBLK_B * 256) {
        float4 x = ((const float4*)pc)[n];
        float h[16];
#pragma unroll
        for (int k = 0; k < 16; ++k) {
            float4 wk = sW4[k];
            float z = x.x * wk.x + x.y * wk.y + x.z * wk.z + x.w * wk.w + sW[64 + k];
            h[k] = (z >= 0.f) ? z : SLOPE * z;
        }
#pragma unroll
        for (int i = 0; i < 16; ++i) acc[i] += h[i];
#pragma unroll
        for (int i = 0; i < 16; ++i)
#pragma unroll
            for (int j = i; j < 16; ++j)
                acc[16 + i * 16 - (i * (i - 1)) / 2 + (j - i)] += h[i] * h[j];
    }

    // wave reduce all 152, then cross-wave via LDS
#pragma unroll
    for (int m = 0; m < 152; ++m) {
        float s = acc[m];
        for (int d = 32; d > 0; d >>= 1) s += __shfl_xor(s, d);
        acc[m] = s;
    }
    if (lane == 0) {
#pragma unroll
        for (int m = 0; m < 152; ++m) sred[w][m] = acc[m];
    }
    __syncthreads();
    if (t < 152)
        pB[t * NBLK_B + blockIdx.x] = sred[0][t] + sred[1][t] + sred[2][t] + sred[3][t];
}

// ---------------- kernel R2: h-moments + W2 -> folded layer-2 weights ----------------
// stats2 layout: [k*64+c] = W2[k][c]*sc2[c] (16x64) ; [1024+c] = b2[c]*sc2[c]+sf2[c]
__global__ __launch_bounds__(1024) void kR2(const float* __restrict__ pB,
                                            const float* __restrict__ W2,
                                            const float* __restrict__ b2,
                                            const float* __restrict__ g2,
                                            const float* __restrict__ be2,
                                            float* __restrict__ stats2) {
    int t = threadIdx.x, w = t >> 6, lane = t & 63;
    __shared__ float S[152];
    for (int q = w; q < 152; q += 16) {
        const float* p = pB + q * NBLK_B;
        float s = p[lane] + p[lane + 64] + p[lane + 128] + p[lane + 192];
        for (int d = 32; d > 0; d >>= 1) s += __shfl_xor(s, d);
        if (lane == 0) S[q] = s;
    }
    __syncthreads();
    if (t < 64) {
        double wv[16];
#pragma unroll
        for (int k = 0; k < 16; ++k) wv[k] = W2[k * 64 + t];
        double sh = 0.0;
        for (int k = 0; k < 16; ++k) sh += wv[k] * (double)S[k];
        auto qidx = [&](int i, int j) { return 16 + i * 16 - (i * (i - 1)) / 2 + (j - i); };
        double q = 0.0;
        for (int i = 0; i < 16; ++i) {
            q += wv[i] * wv[i] * (double)S[qidx(i, i)];
            double t2 = 0.0;
            for (int j = i + 1; j < 16; ++j) t2 += wv[j] * (double)S[qidx(i, j)];
            q += 2.0 * wv[i] * t2;
        }
        double b = (double)b2[t];
        double sum   = sh + b * (double)N_PTS;
        double sumsq = q + 2.0 * b * sh + (double)N_PTS * b * b;
        double mean = sum / (double)N_PTS;
        double var  = sumsq / (double)N_PTS - mean * mean;
        float inv = rsqrtf((float)(var + 1e-5));
        float sc = g2[t] * inv;
        float sf = be2[t] - (float)mean * sc;
#pragma unroll
        for (int k = 0; k < 16; ++k) stats2[k * 64 + t] = W2[k * 64 + t] * sc;
        stats2[1024 + t] = b2[t] * sc + sf;
    }
}

// ---------------- scan pass 1 ----------------
__global__ __launch_bounds__(256) void kS1(const u32* __restrict__ cnt,
                                           u32* __restrict__ bsum) {
    int t = threadIdx.x, b = blockIdx.x;
    uint4 c4 = ((const uint4*)cnt)[b * 256 + t];
    u32 cs = c4.x + c4.y + c4.z + c4.w;
    u32 os = (c4.x > 0) + (c4.y > 0) + (c4.z > 0) + (c4.w > 0);
    __shared__ u32 rc[256], ro[256];
    rc[t] = cs; ro[t] = os;
    __syncthreads();
    for (int s = 128; s > 0; s >>= 1) {
        if (t < s) { rc[t] += rc[t + s]; ro[t] += ro[t + s]; }
        __syncthreads();
    }
    if (t == 0) { bsum[2 * b] = rc[0]; bsum[2 * b + 1] = ro[0]; }
}

// ---------------- scan pass 2: cursors, startc, vi rows, n_uni ----------------
__global__ __launch_bounds__(256) void kS2(u32* __restrict__ cnt,
                                           const u32* __restrict__ bsum,
                                           u32* __restrict__ startc,
                                           float* __restrict__ vi,
                                           u32* __restrict__ nuni) {
    int t = threadIdx.x, b = blockIdx.x;
    __shared__ u32 sbc[128], sbo[128];
    __shared__ u32 cOff, oOff;
    __shared__ u64 scan[256];
    if (t < 128) { sbc[t] = bsum[2 * t]; sbo[t] = bsum[2 * t + 1]; }

    uint4 c4 = ((const uint4*)cnt)[b * 256 + t];
    u32 cv[4] = { c4.x, c4.y, c4.z, c4.w };
    u32 cs = cv[0] + cv[1] + cv[2] + cv[3];
    u32 os = (cv[0] > 0) + (cv[1] > 0) + (cv[2] > 0) + (cv[3] > 0);
    scan[t] = ((u64)cs << 32) | (u64)os;
    __syncthreads();
    if (t == 0) {
        u32 a = 0, o = 0;
        for (int i = 0; i < b; ++i) { a += sbc[i]; o += sbo[i]; }
        cOff = a; oOff = o;
    }
    for (int d = 1; d < 256; d <<= 1) {
        u64 v = (t >= d) ? scan[t - d] : 0ull;
        __syncthreads();
        scan[t] += v;
        __syncthreads();
    }
    u64 ex = scan[t] - (((u64)cs << 32) | (u64)os);
    u32 start = cOff + (u32)(ex >> 32);
    u32 rank  = oOff + (u32)(ex & 0xffffffffull);

    int kbase = b * 1024 + t * 4;
#pragma unroll
    for (int j = 0; j < 4; ++j) {
        u32 k = (u32)(kbase + j);
        cnt[k] = start;
        if (cv[j] > 0) {
            startc[rank] = start;
            float4 o;
            o.x = (float)(k >> 15);
            o.y = (float)((k >> 10) & 31);
            o.z = (float)((k >> 5) & 31);
            o.w = (float)(k & 31);
            ((float4*)vi)[rank] = o;
            rank++;
        }
        start += cv[j];
    }
    if (b == 127 && t == 255) {
        nuni[0] = rank;
        startc[rank] = N_PTS;
    }
}

// ---------------- kernel P: scatter point ids into voxel-sorted order ----------------
__global__ __launch_bounds__(256) void kP(const u32* __restrict__ keys,
                                          u32* __restrict__ cursor,
                                          u32* __restrict__ pid) {
    int n = blockIdx.x * 256 + threadIdx.x;
    if (n < N_PTS) {
        u32 k = keys[n];
        u32 pos = atomicAdd(&cursor[k], 1u);
        pid[pos] = (u32)n;
    }
}

// ---------------- kernel C: MLP with bf16-packed h staging, write feat ----------------
__global__ __launch_bounds__(256) void kC(const float* __restrict__ pc,
                                          const float* __restrict__ stats1,
                                          const float* __restrict__ stats2,
                                          float* __restrict__ feat_out) {
    int t = threadIdx.x;
    __shared__ u32 shp[64][8];     // h as bf16 pairs: shp[p][q] = {ch 2q lo, ch 2q+1 hi}

    // h-phase identity: channel pair cpair = t&7, point sub = t>>3 (32 points/half)
    int cpair = t & 7, psub = t >> 3;
    float w1a[4], w1b[4], c1a, c1b;
#pragma unroll
    for (int i = 0; i < 4; ++i) {
        w1a[i] = stats1[(2 * cpair) * 4 + i];
        w1b[i] = stats1[(2 * cpair + 1) * 4 + i];
    }
    c1a = stats1[64 + 2 * cpair];
    c1b = stats1[64 + 2 * cpair + 1];

    // f-phase identity: channel c2 = t&63, wave pg = t>>6
    int c2 = t & 63, pg = t >> 6;
    float w2c[16];
#pragma unroll
    for (int k = 0; k < 16; ++k) w2c[k] = stats2[k * 64 + c2];
    float c2fr = stats2[1024 + c2];

    for (int tile = blockIdx.x; tile < NT64; tile += gridDim.x) {
        int base = tile * 64;
#pragma unroll
        for (int half = 0; half < 2; ++half) {
            int p = psub + 32 * half;
            float4 x = ((const float4*)pc)[base + p];
            float za = x.x * w1a[0] + x.y * w1a[1] + x.z * w1a[2] + x.w * w1a[3] + c1a;
            float zb = x.x * w1b[0] + x.y * w1b[1] + x.z * w1b[2] + x.w * w1b[3] + c1b;
            za = (za >= 0.f) ? za : SLOPE * za;
            zb = (zb >= 0.f) ? zb : SLOPE * zb;
            shp[p][cpair] = bf16pack(za, zb);
        }
        __syncthreads();
#pragma unroll
        for (int j = 0; j < 16; ++j) {
            int p = pg + 4 * j;
            const uint4* row = (const uint4*)&shp[p][0];
            uint4 v0 = row[0], v1 = row[1];
            float f = c2fr;
            f += bf_lo(v0.x) * w2c[0]  + bf_hi(v0.x) * w2c[1];
            f += bf_lo(v0.y) * w2c[2]  + bf_hi(v0.y) * w2c[3];
            f += bf_lo(v0.z) * w2c[4]  + bf_hi(v0.z) * w2c[5];
            f += bf_lo(v0.w) * w2c[6]  + bf_hi(v0.w) * w2c[7];
            f += bf_lo(v1.x) * w2c[8]  + bf_hi(v1.x) * w2c[9];
            f += bf_lo(v1.y) * w2c[10] + bf_hi(v1.y) * w2c[11];
            f += bf_lo(v1.z) * w2c[12] + bf_hi(v1.z) * w2c[13];
            f += bf_lo(v1.w) * w2c[14] + bf_hi(v1.w) * w2c[15];
            float ff = (f >= 0.f) ? f : SLOPE * f;
            feat_out[(size_t)(base + p) * 64 + c2] = ff;
        }
        __syncthreads();
    }
}

// ---------------- kernel V: gather-max per voxel rank; zero tails ----------------
__global__ __launch_bounds__(256) void kV(const float* __restrict__ feat,
                                          const u32* __restrict__ pid,
                                          const u32* __restrict__ startc,
                                          const u32* __restrict__ nuni,
                                          float* __restrict__ vf,
                                          float* __restrict__ vi) {
    u32 nu = *nuni;
    u32 r0 = blockIdx.x * 4;
    int w = threadIdx.x >> 6, lane = threadIdx.x & 63;

    if (threadIdx.x < 16) {
        u32 row = r0 + (threadIdx.x >> 2);
        if (row >= nu) vi[(size_t)row * 4 + (threadIdx.x & 3)] = 0.f;
    }

    u32 r = r0 + (u32)w;
    if (r < nu) {
        u32 s = startc[r], e = startc[r + 1];
        float m = -3.4e38f;
        for (u32 i = s; i < e; ++i) {
            u32 p = pid[i];
            m = fmaxf(m, feat[(size_t)p * 64 + lane]);
        }
        vf[(size_t)r * 64 + lane] = m;
    } else {
        vf[(size_t)r * 64 + lane] = 0.f;
    }
}

extern "C" void kernel_launch(void* const* d_in, const int* in_sizes, int n_in,
                              void* d_out, int out_size, void* d_ws, size_t ws_size,
                              hipStream_t stream) {
    const float* pc   = (const float*)d_in[0];
    const int*   pidx = (const int*)d_in[1];
    const float* W1   = (const float*)d_in[2];
    const float* b1   = (const float*)d_in[3];
    const float* g1   = (const float*)d_in[4];
    const float* be1  = (const float*)d_in[5];
    const float* W2   = (const float*)d_in[6];
    const float* b2   = (const float*)d_in[7];
    const float* g2   = (const float*)d_in[8];
    const float* be2  = (const float*)d_in[9];

    float* vf   = (float*)d_out;                    // [N,64]
    float* vi   = vf + (size_t)N_PTS * 64;          // [N,4]
    float* feat = vi + (size_t)N_PTS * 4;           // [N,64]

    u32* ws     = (u32*)d_ws;
    u32* keys   = ws;                        // 480000
    u32* cnt    = ws + 480000;               // 131072 (becomes cursor)
    u32* startc = ws + 611072;               // 131073 (+pad)
    u32* bsum   = ws + 742148;               // 256
    u32* nuni   = ws + 742404;               // 1 (+pad)
    u32* pid    = ws + 742420;               // 480000
    float* pA     = (float*)(ws + 1222420);  // 14*256 = 3584
    float* stats1 = (float*)(ws + 1226004);  // 80
    float* pB     = (float*)(ws + 1226084);  // 152*256 = 38912
    float* stats2 = (float*)(ws + 1264996);  // 1088

    kZ<<<128, 256, 0, stream>>>(cnt);
    kA<<<NBLK_A, 256, 0, stream>>>(pc, pidx, keys, cnt, pA);
    kR1<<<1, 1024, 0, stream>>>(pA, W1, b1, g1, be1, stats1);
    kB<<<NBLK_B, 256, 0, stream>>>(pc, stats1, pB);
    kR2<<<1, 1024, 0, stream>>>(pB, W2, b2, g2, be2, stats2);
    kS1<<<128, 256, 0, stream>>>(cnt, bsum);
    kS2<<<128, 256, 0, stream>>>(cnt, bsum, startc, vi, nuni);
    kP<<<1875, 256, 0, stream>>>(keys, cnt, pid);
    kC<<<2048, 256, 0, stream>>>(pc, stats1, stats2, feat);
    kV<<<120000, 256, 0, stream>>>(feat, pid, startc, nuni, vf, vi);
}